// Round 12
// baseline (375.865 us; speedup 1.0000x reference)
//
#include <hip/hip_runtime.h>

// MUTAN fused bilinear (low-rank Tucker) + ReLU + LayerNorm, MI355X gfx950.
// Round 12: T4 retrofit on round-11. Raw s_barrier + counted s_waitcnt
// vmcnt(8) (stage distance 2, never drain in main loop); rank-boundary
// Hadamard exchange via dedicated 16 KB LDS buffer (2-round publish/consume).

typedef unsigned short u16;
typedef __attribute__((ext_vector_type(8)))  short bf16x8;   // 8 bf16
typedef __attribute__((ext_vector_type(16))) float f32x16;   // 32x32 MFMA C/D

constexpr int Bq = 4096;   // batch
constexpr int D  = 1024;   // contraction dim
constexpr int Zq = 1024;   // output dim
constexpr int Rk = 16;     // rank
// A pack: [bx(32)][kt(16)][chunk(1024)][8]; chunk = (mfb*4+ks)*64 + lane
//   row = bx*128 + mfb*32 + (l&31), k = kt*64 + ks*16 + 8*(l>>5) + e
// B pack: [r(16)][jt(8)][kt(16)][chunk(1024)][8]; chunk = (nfb*4+ks)*64 + lane
// 32x32x16 frags: A[l&31][8*(l>>5)+e]; B[8*(l>>5)+e][l&31];
// C/D (verified m74/m101): col = lane&31, row = (reg&3)+8*(reg>>2)+4*(lane>>5).

typedef const __attribute__((address_space(1))) void* gas_t;
typedef __attribute__((address_space(3))) void* las_t;

__device__ __forceinline__ u16 f2b(float f) {
  union { float f; unsigned u; } c; c.f = f;
  unsigned r = (c.u + 0x7FFFu + ((c.u >> 16) & 1u)) >> 16;  // RNE
  return (u16)r;
}
__device__ __forceinline__ float b2f(u16 h) {
  union { unsigned u; float f; } c; c.u = ((unsigned)h) << 16; return c.f;
}

// ---- prep: hd/hp [4096][1024] f32 -> fragment-major bf16 (32-row frags) ----
__global__ __launch_bounds__(256) void fm_pack_A(const float* __restrict__ src,
                                                 u16* __restrict__ dst) {
  const int g  = blockIdx.x * 256 + threadIdx.x;      // chunk id (524288)
  const int c  = g & 1023;
  const int kt = (g >> 10) & 15;
  const int bx = g >> 14;
  const int l   = c & 63;
  const int ks  = (c >> 6) & 3;
  const int mfb = c >> 8;                              // 0..3
  const int row = bx * 128 + mfb * 32 + (l & 31);
  const int kb  = kt * 64 + ks * 16 + ((l >> 5) << 3);
  const float* s = src + (size_t)row * D + kb;
  const float4 f0 = *(const float4*)s;
  const float4 f1 = *(const float4*)(s + 4);
  union { u16 h[8]; uint4 u; } o;
  o.h[0] = f2b(f0.x); o.h[1] = f2b(f0.y); o.h[2] = f2b(f0.z); o.h[3] = f2b(f0.w);
  o.h[4] = f2b(f1.x); o.h[5] = f2b(f1.y); o.h[6] = f2b(f1.z); o.h[7] = f2b(f1.w);
  *(uint4*)(dst + (size_t)g * 8) = o.u;
}

// ---- prep: U/V [r][k][z] f32 -> fragment-major bf16 (32-col frags) ----
__global__ __launch_bounds__(256) void fm_pack_B(const float* __restrict__ src,
                                                 u16* __restrict__ dst) {
  const int g  = blockIdx.x * 256 + threadIdx.x;      // chunk id (2097152)
  const int c  = g & 1023;
  const int kt = (g >> 10) & 15;
  const int jt = (g >> 14) & 7;
  const int r  = g >> 17;
  const int l   = c & 63;
  const int ks  = (c >> 6) & 3;
  const int nfb = c >> 8;                              // 0..3
  const int col = jt * 128 + nfb * 32 + (l & 31);
  const int kg  = kt * 64 + ks * 16 + ((l >> 5) << 3);
  const float* s = src + (size_t)r * (D * Zq) + (size_t)kg * Zq + col;
  union { u16 h[8]; uint4 u; } o;
  #pragma unroll
  for (int e = 0; e < 8; ++e) o.h[e] = f2b(s[(size_t)e * Zq]);
  *(uint4*)(dst + (size_t)g * 8) = o.u;
}

#define GLDS(src, dst) __builtin_amdgcn_global_load_lds((gas_t)(src), (las_t)(dst), 16, 0, 0)
#define MFMA32(a, b, c) __builtin_amdgcn_mfma_f32_32x32x16_bf16(a, b, c, 0, 0, 0)
#define SFENCE() __builtin_amdgcn_sched_barrier(0)
#define BAR()    __builtin_amdgcn_s_barrier()

#define STAGE_A(buf, st) do {                                                    \
    const int _kt = (st) & 15;                                                   \
    GLDS(hdp + _kt * 8192 + c0 * 8, &sT[buf][0][c0 * 8]);                        \
    GLDS(hdp + _kt * 8192 + c1 * 8, &sT[buf][0][c1 * 8]);                        \
    GLDS(hpp + _kt * 8192 + c0 * 8, &sT[buf][1][c0 * 8]);                        \
    GLDS(hpp + _kt * 8192 + c1 * 8, &sT[buf][1][c1 * 8]);                        \
  } while (0)

#define STAGE_B(buf, st) do {                                                    \
    const int _kt = (st) & 15;                                                   \
    const u16* _u = Ub + (size_t)((st) >> 4) * rstride + _kt * 8192;             \
    const u16* _v = Vb + (size_t)((st) >> 4) * rstride + _kt * 8192;             \
    GLDS(_u + c0 * 8, &sT[buf][2][c0 * 8]);                                      \
    GLDS(_u + c1 * 8, &sT[buf][2][c1 * 8]);                                      \
    GLDS(_v + c0 * 8, &sT[buf][3][c0 * 8]);                                      \
    GLDS(_v + c1 * 8, &sT[buf][3][c1 * 8]);                                      \
  } while (0)

// role-split compute: each wave reads ONE A tensor + ONE B tensor, 16 MFMA.
#define COMPUTE(buf) do {                                                        \
    const u16* tA = sT[buf][role];                                               \
    const u16* tB = sT[buf][2 + role];                                           \
    _Pragma("unroll")                                                            \
    for (int ks = 0; ks < 4; ++ks) {                                             \
      bf16x8 a0 = *(const bf16x8*)(tA + (((wm * 2 + 0) * 4 + ks) * 64 + lane) * 8); \
      bf16x8 a1 = *(const bf16x8*)(tA + (((wm * 2 + 1) * 4 + ks) * 64 + lane) * 8); \
      bf16x8 b0 = *(const bf16x8*)(tB + (((wn * 2 + 0) * 4 + ks) * 64 + lane) * 8); \
      bf16x8 b1 = *(const bf16x8*)(tB + (((wn * 2 + 1) * 4 + ks) * 64 + lane) * 8); \
      __builtin_amdgcn_s_setprio(1);                                             \
      aw[0][0] = MFMA32(a0, b0, aw[0][0]);                                       \
      aw[0][1] = MFMA32(a0, b1, aw[0][1]);                                       \
      aw[1][0] = MFMA32(a1, b0, aw[1][0]);                                       \
      aw[1][1] = MFMA32(a1, b1, aw[1][1]);                                       \
      __builtin_amdgcn_s_setprio(0);                                             \
    }                                                                            \
  } while (0)

// ---- main: fused bilinear, role-split 32x32x16 MFMA, counted-vmcnt ----
// grid (32 bx, 8 jt) = 256 blocks = 1/CU. 512 thr = 8 waves: 0-3 u-GEMM
// (hd*U), 4-7 v-GEMM (hp*V); wave tile 64x64 (2x2 frags of 32x32).
// Stage distance 2, s_waitcnt vmcnt(8) (never 0 in main loop).
// Rank boundary: 2-round av exchange via dedicated 16 KB LDS buffer.
__global__ __launch_bounds__(512, 2) void fused_bilinear(
    const u16* __restrict__ hdf, const u16* __restrict__ hpf,
    const u16* __restrict__ Uf, const u16* __restrict__ Vf,
    float* __restrict__ out)
{
  __shared__ __align__(16) u16 sT[2][4][8192];     // 128 KB: [buf][hd,hp,U,V]
  __shared__ __align__(16) unsigned exch2[4096];   // 16 KB exchange

  const int tid  = threadIdx.x;
  const int lane = tid & 63;
  const int wid  = tid >> 6;
  const int role = wid >> 2;              // 0 = u (hd*U), 1 = v (hp*V)
  const int w4   = wid & 3;
  const int wm   = w4 >> 1;               // 0..1
  const int wn   = w4 & 1;                // 0..1

  const int bx = blockIdx.x;              // 0..31 (XCD = bx%8)
  const int jt = blockIdx.y;              // 0..7

  const u16* hdp = hdf + (size_t)bx * 16 * 8192;     // [kt][1024 chunks][8]
  const u16* hpp = hpf + (size_t)bx * 16 * 8192;
  const u16* Ub  = Uf + (size_t)jt * 16 * 8192;      // + r*rstride + kt*8192
  const u16* Vb  = Vf + (size_t)jt * 16 * 8192;
  const size_t rstride = (size_t)8 * 16 * 8192;

  const int c0 = tid;                     // staging chunks per tensor
  const int c1 = tid + 512;

  f32x16 acc[2][2], aw[2][2];
  #pragma unroll
  for (int mf = 0; mf < 2; ++mf)
    #pragma unroll
    for (int nf = 0; nf < 2; ++nf) {
      #pragma unroll
      for (int i = 0; i < 16; ++i) { acc[mf][nf][i] = 0.f; aw[mf][nf][i] = 0.f; }
    }

  // prologue: stage steps 0 (buf0) and 1 (buf1); retire step-0 group only.
  STAGE_A(0, 0); STAGE_B(0, 0);
  STAGE_A(1, 1); STAGE_B(1, 1);
  SFENCE();
  asm volatile("s_waitcnt vmcnt(8)" ::: "memory");
  SFENCE();
  BAR(); SFENCE();

  #pragma unroll 1
  for (int it = 0; it < 128; ++it) {
    const int s0 = it * 2, s1 = s0 + 1;

    // ---- even step: compute buf0; refill buf0 <- s0+2; retire stage(s0+1)
    COMPUTE(0);
    SFENCE(); BAR(); SFENCE();            // all waves done reading buf0
    if (s0 + 2 < 256) {
      STAGE_A(0, s0 + 2); STAGE_B(0, s0 + 2);
      SFENCE();
      asm volatile("s_waitcnt vmcnt(8)" ::: "memory");
    } else {
      SFENCE();
      asm volatile("s_waitcnt vmcnt(0)" ::: "memory");
    }
    SFENCE(); BAR(); SFENCE();            // buf1 (step s1) published

    // ---- odd step: compute buf1; boundary exchange; refill buf1; retire
    COMPUTE(1);
    SFENCE(); BAR(); SFENCE();            // all waves done reading buf1
    const bool bound = ((s1 & 15) == 15);
    if (bound) {
      #pragma unroll
      for (int g = 0; g < 2; ++g) {
        if (role) {                       // v-waves publish aw[g][*] as bf16
          #pragma unroll
          for (int nf = 0; nf < 2; ++nf)
            #pragma unroll
            for (int rp = 0; rp < 8; ++rp) {
              const unsigned lo = f2b(aw[g][nf][2 * rp]);
              const unsigned hi = f2b(aw[g][nf][2 * rp + 1]);
              exch2[((w4 * 2 + nf) * 8 + rp) * 64 + lane] = lo | (hi << 16);
            }
          asm volatile("s_waitcnt lgkmcnt(0)" ::: "memory");
        }
        SFENCE(); BAR(); SFENCE();
        if (!role) {                      // u-waves: acc += au * av
          #pragma unroll
          for (int nf = 0; nf < 2; ++nf)
            #pragma unroll
            for (int rp = 0; rp < 8; ++rp) {
              const unsigned w = exch2[((w4 * 2 + nf) * 8 + rp) * 64 + lane];
              acc[g][nf][2 * rp]     += aw[g][nf][2 * rp]     * b2f((u16)(w & 0xFFFFu));
              acc[g][nf][2 * rp + 1] += aw[g][nf][2 * rp + 1] * b2f((u16)(w >> 16));
            }
        }
        if (g == 0) { SFENCE(); BAR(); SFENCE(); }   // round-0 consumed
      }
    }
    if (s1 + 2 < 256) {
      STAGE_A(1, s1 + 2); STAGE_B(1, s1 + 2);
      SFENCE();
      asm volatile("s_waitcnt vmcnt(8)" ::: "memory");
    } else {
      SFENCE();
      asm volatile("s_waitcnt vmcnt(0)" ::: "memory");
    }
    SFENCE(); BAR(); SFENCE();            // buf0 (step s0+2) published
    if (bound) {
      #pragma unroll
      for (int mf = 0; mf < 2; ++mf)
        #pragma unroll
        for (int nf = 0; nf < 2; ++nf)
          #pragma unroll
          for (int i = 0; i < 16; ++i) aw[mf][nf][i] = 0.f;
    }
  }

  // epilogue: u-waves store RAW rank-sum (ReLU in LN).
  // D-layout 32x32: col = lane&31, row = (reg&3) + 8*(reg>>2) + 4*(lane>>5).
  if (!role) {
    const int brow = bx * 128 + wm * 64;
    const int jcol = jt * 128 + wn * 64;
    #pragma unroll
    for (int mf = 0; mf < 2; ++mf)
      #pragma unroll
      for (int nf = 0; nf < 2; ++nf) {
        #pragma unroll
        for (int i = 0; i < 16; ++i) {
          const int row = brow + mf * 32 + (i & 3) + 8 * (i >> 2) + 4 * (lane >> 5);
          const int col = jcol + nf * 32 + (lane & 31);
          out[(size_t)row * Zq + col] = acc[mf][nf][i];
        }
      }
  }
}

// ---- LayerNorm: z = relu(p); LN(z) -> out, in place. jnp.var ddof=0. ----
__global__ __launch_bounds__(256) void ln_rows(float* __restrict__ out,
    const float* __restrict__ gamma, const float* __restrict__ beta)
{
  const int row = blockIdx.x;
  const int t = threadIdx.x;
  float* o = out + (size_t)row * Zq;
  float4 v = ((const float4*)o)[t];
  v.x = fmaxf(v.x, 0.f); v.y = fmaxf(v.y, 0.f);
  v.z = fmaxf(v.z, 0.f); v.w = fmaxf(v.w, 0.f);
  float s = v.x + v.y + v.z + v.w;
  float q = v.x * v.x + v.y * v.y + v.z * v.z + v.w * v.w;
  #pragma unroll
  for (int off = 32; off > 0; off >>= 1) {
    s += __shfl_xor(s, off);
    q += __shfl_xor(q, off);
  }
  __shared__ float ss[4], sq[4];
  if ((t & 63) == 0) { ss[t >> 6] = s; sq[t >> 6] = q; }
  __syncthreads();
  s = ss[0] + ss[1] + ss[2] + ss[3];
  q = sq[0] + sq[1] + sq[2] + sq[3];
  const float mean = s * (1.f / Zq);
  float var = q * (1.f / Zq) - mean * mean;
  var = fmaxf(var, 0.f);
  const float rstd = rsqrtf(var + 1e-5f);
  const float4 g  = ((const float4*)gamma)[t];
  const float4 bb = ((const float4*)beta)[t];
  v.x = (v.x - mean) * rstd * g.x + bb.x;
  v.y = (v.y - mean) * rstd * g.y + bb.y;
  v.z = (v.z - mean) * rstd * g.z + bb.z;
  v.w = (v.w - mean) * rstd * g.w + bb.w;
  ((float4*)o)[t] = v;
}

// ---- fallback (tiny ws): plain f32, correct but slow ----
__global__ __launch_bounds__(256) void fallback_bilinear(
    const float* __restrict__ hd, const float* __restrict__ hp,
    const float* __restrict__ U, const float* __restrict__ V,
    float* __restrict__ out)
{
  const int j  = blockIdx.x * 256 + threadIdx.x;
  const int b0 = blockIdx.y * 8;
  float acc[8] = {0.f, 0.f, 0.f, 0.f, 0.f, 0.f, 0.f, 0.f};
  for (int r = 0; r < Rk; ++r) {
    float u[8] = {0.f}, v[8] = {0.f};
    const float* Up = U + (size_t)r * (D * Zq) + j;
    const float* Vp = V + (size_t)r * (D * Zq) + j;
    for (int k = 0; k < D; ++k) {
      const float uu = Up[(size_t)k * Zq];
      const float vv = Vp[(size_t)k * Zq];
      #pragma unroll
      for (int bi = 0; bi < 8; ++bi) {
        u[bi] = fmaf(hd[(size_t)(b0 + bi) * D + k], uu, u[bi]);
        v[bi] = fmaf(hp[(size_t)(b0 + bi) * D + k], vv, v[bi]);
      }
    }
    #pragma unroll
    for (int bi = 0; bi < 8; ++bi) acc[bi] += u[bi] * v[bi];
  }
  #pragma unroll
  for (int bi = 0; bi < 8; ++bi)
    out[(size_t)(b0 + bi) * Zq + j] = acc[bi];   // raw; ReLU in LN
}

extern "C" void kernel_launch(void* const* d_in, const int* in_sizes, int n_in,
                              void* d_out, int out_size, void* d_ws, size_t ws_size,
                              hipStream_t stream) {
  const float* hd    = (const float*)d_in[0];   // [4096][1024]
  const float* hp    = (const float*)d_in[1];   // [4096][1024]
  const float* U     = (const float*)d_in[2];   // [16][1024][1024]
  const float* V     = (const float*)d_in[3];   // [16][1024][1024]
  const float* gamma = (const float*)d_in[4];   // [1024]
  const float* beta  = (const float*)d_in[5];   // [1024]
  float* out = (float*)d_out;                   // [4096][1024] f32

  const size_t need = 80ull << 20;  // hd,hp fm (16MB) + U,V fm (64MB)
  if (ws_size >= need) {
    u16* hdf = (u16*)d_ws;                   // 4M elems
    u16* hpf = hdf + (size_t)Bq * D;
    u16* Ufm = hpf + (size_t)Bq * D;         // 16M elems each
    u16* Vfm = Ufm + (size_t)Rk * D * Zq;

    fm_pack_A<<<2048, 256, 0, stream>>>(hd, hdf);
    fm_pack_A<<<2048, 256, 0, stream>>>(hp, hpf);
    fm_pack_B<<<8192, 256, 0, stream>>>(U, Ufm);
    fm_pack_B<<<8192, 256, 0, stream>>>(V, Vfm);
    fused_bilinear<<<dim3(32, 8), 512, 0, stream>>>(hdf, hpf, Ufm, Vfm, out);
  } else {
    fallback_bilinear<<<dim3(Zq / 256, Bq / 8), 256, 0, stream>>>(hd, hp, U, V, out);
  }
  ln_rows<<<Bq, 256, 0, stream>>>(out, gamma, beta);
}

// Round 13
// 359.397 us; speedup vs baseline: 1.0458x; 1.0458x over previous
//
#include <hip/hip_runtime.h>

// MUTAN fused bilinear (low-rank Tucker) + ReLU + LayerNorm, MI355X gfx950.
// Round 13: consolidation on the round-11 winner (308us). Round-11 schedule
// (stage at top of step, single __syncthreads drain) + dedicated 16KB
// exchange buffer (uniform staging at rank boundaries, r12's proven 2-round
// publish/consume) + merged prep launches. r12's T4 retrofit reverted
// (regressed: stage-issue serialized between barriers).

typedef unsigned short u16;
typedef __attribute__((ext_vector_type(8)))  short bf16x8;   // 8 bf16
typedef __attribute__((ext_vector_type(16))) float f32x16;   // 32x32 MFMA C/D

constexpr int Bq = 4096;   // batch
constexpr int D  = 1024;   // contraction dim
constexpr int Zq = 1024;   // output dim
constexpr int Rk = 16;     // rank
// A pack: [bx(32)][kt(16)][chunk(1024)][8]; chunk = (mfb*4+ks)*64 + lane
//   row = bx*128 + mfb*32 + (l&31), k = kt*64 + ks*16 + 8*(l>>5) + e
// B pack: [r(16)][jt(8)][kt(16)][chunk(1024)][8]; chunk = (nfb*4+ks)*64 + lane
// 32x32x16 frags: A[l&31][8*(l>>5)+e]; B[8*(l>>5)+e][l&31];
// C/D (verified m74/m101): col = lane&31, row = (reg&3)+8*(reg>>2)+4*(lane>>5).

typedef const __attribute__((address_space(1))) void* gas_t;
typedef __attribute__((address_space(3))) void* las_t;

__device__ __forceinline__ u16 f2b(float f) {
  union { float f; unsigned u; } c; c.f = f;
  unsigned r = (c.u + 0x7FFFu + ((c.u >> 16) & 1u)) >> 16;  // RNE
  return (u16)r;
}
__device__ __forceinline__ float b2f(u16 h) {
  union { unsigned u; float f; } c; c.u = ((unsigned)h) << 16; return c.f;
}

// ---- prep: hd & hp [4096][1024] f32 -> fragment-major bf16 (merged) ----
__global__ __launch_bounds__(256) void fm_pack_A2(const float* __restrict__ sA,
                                                  const float* __restrict__ sB,
                                                  u16* __restrict__ dA,
                                                  u16* __restrict__ dB) {
  const float* src = blockIdx.y ? sB : sA;
  u16* dst = blockIdx.y ? dB : dA;
  const int g  = blockIdx.x * 256 + threadIdx.x;      // chunk id (524288)
  const int c  = g & 1023;
  const int kt = (g >> 10) & 15;
  const int bx = g >> 14;
  const int l   = c & 63;
  const int ks  = (c >> 6) & 3;
  const int mfb = c >> 8;                              // 0..3
  const int row = bx * 128 + mfb * 32 + (l & 31);
  const int kb  = kt * 64 + ks * 16 + ((l >> 5) << 3);
  const float* s = src + (size_t)row * D + kb;
  const float4 f0 = *(const float4*)s;
  const float4 f1 = *(const float4*)(s + 4);
  union { u16 h[8]; uint4 u; } o;
  o.h[0] = f2b(f0.x); o.h[1] = f2b(f0.y); o.h[2] = f2b(f0.z); o.h[3] = f2b(f0.w);
  o.h[4] = f2b(f1.x); o.h[5] = f2b(f1.y); o.h[6] = f2b(f1.z); o.h[7] = f2b(f1.w);
  *(uint4*)(dst + (size_t)g * 8) = o.u;
}

// ---- prep: U & V [r][k][z] f32 -> fragment-major bf16 (merged) ----
__global__ __launch_bounds__(256) void fm_pack_B2(const float* __restrict__ sU,
                                                  const float* __restrict__ sV,
                                                  u16* __restrict__ dU,
                                                  u16* __restrict__ dV) {
  const float* src = blockIdx.y ? sV : sU;
  u16* dst = blockIdx.y ? dV : dU;
  const int g  = blockIdx.x * 256 + threadIdx.x;      // chunk id (2097152)
  const int c  = g & 1023;
  const int kt = (g >> 10) & 15;
  const int jt = (g >> 14) & 7;
  const int r  = g >> 17;
  const int l   = c & 63;
  const int ks  = (c >> 6) & 3;
  const int nfb = c >> 8;                              // 0..3
  const int col = jt * 128 + nfb * 32 + (l & 31);
  const int kg  = kt * 64 + ks * 16 + ((l >> 5) << 3);
  const float* s = src + (size_t)r * (D * Zq) + (size_t)kg * Zq + col;
  union { u16 h[8]; uint4 u; } o;
  #pragma unroll
  for (int e = 0; e < 8; ++e) o.h[e] = f2b(s[(size_t)e * Zq]);
  *(uint4*)(dst + (size_t)g * 8) = o.u;
}

#define GLDS(src, dst) __builtin_amdgcn_global_load_lds((gas_t)(src), (las_t)(dst), 16, 0, 0)
#define MFMA32(a, b, c) __builtin_amdgcn_mfma_f32_32x32x16_bf16(a, b, c, 0, 0, 0)
#define BAR() __builtin_amdgcn_s_barrier()

#define STAGE_A(buf, st) do {                                                    \
    const int _kt = (st) & 15;                                                   \
    GLDS(hdp + _kt * 8192 + c0 * 8, &sT[buf][0][c0 * 8]);                        \
    GLDS(hdp + _kt * 8192 + c1 * 8, &sT[buf][0][c1 * 8]);                        \
    GLDS(hpp + _kt * 8192 + c0 * 8, &sT[buf][1][c0 * 8]);                        \
    GLDS(hpp + _kt * 8192 + c1 * 8, &sT[buf][1][c1 * 8]);                        \
  } while (0)

#define STAGE_B(buf, st) do {                                                    \
    const int _kt = (st) & 15;                                                   \
    const u16* _u = Ub + (size_t)((st) >> 4) * rstride + _kt * 8192;             \
    const u16* _v = Vb + (size_t)((st) >> 4) * rstride + _kt * 8192;             \
    GLDS(_u + c0 * 8, &sT[buf][2][c0 * 8]);                                      \
    GLDS(_u + c1 * 8, &sT[buf][2][c1 * 8]);                                      \
    GLDS(_v + c0 * 8, &sT[buf][3][c0 * 8]);                                      \
    GLDS(_v + c1 * 8, &sT[buf][3][c1 * 8]);                                      \
  } while (0)

// role-split compute: each wave reads ONE A tensor + ONE B tensor, 16 MFMA.
#define COMPUTE(buf) do {                                                        \
    const u16* tA = sT[buf][role];                                               \
    const u16* tB = sT[buf][2 + role];                                           \
    _Pragma("unroll")                                                            \
    for (int ks = 0; ks < 4; ++ks) {                                             \
      bf16x8 a0 = *(const bf16x8*)(tA + (((wm * 2 + 0) * 4 + ks) * 64 + lane) * 8); \
      bf16x8 a1 = *(const bf16x8*)(tA + (((wm * 2 + 1) * 4 + ks) * 64 + lane) * 8); \
      bf16x8 b0 = *(const bf16x8*)(tB + (((wn * 2 + 0) * 4 + ks) * 64 + lane) * 8); \
      bf16x8 b1 = *(const bf16x8*)(tB + (((wn * 2 + 1) * 4 + ks) * 64 + lane) * 8); \
      __builtin_amdgcn_s_setprio(1);                                             \
      aw[0][0] = MFMA32(a0, b0, aw[0][0]);                                       \
      aw[0][1] = MFMA32(a0, b1, aw[0][1]);                                       \
      aw[1][0] = MFMA32(a1, b0, aw[1][0]);                                       \
      aw[1][1] = MFMA32(a1, b1, aw[1][1]);                                       \
      __builtin_amdgcn_s_setprio(0);                                             \
    }                                                                            \
  } while (0)

// ---- main: fused bilinear, role-split 32x32x16 MFMA (round-11 schedule) ----
// grid (32 bx, 8 jt) = 256 blocks = 1/CU. 512 thr = 8 waves: 0-3 u-GEMM
// (hd*U), 4-7 v-GEMM (hp*V); wave tile 64x64 (2x2 frags of 32x32).
// Per step: stage next tile (other buf) -> COMPUTE(cur) -> __syncthreads.
// Rank boundary: 2-round av exchange via dedicated 16 KB LDS buffer.
__global__ __launch_bounds__(512, 2) void fused_bilinear(
    const u16* __restrict__ hdf, const u16* __restrict__ hpf,
    const u16* __restrict__ Uf, const u16* __restrict__ Vf,
    float* __restrict__ out)
{
  __shared__ __align__(16) u16 sT[2][4][8192];     // 128 KB: [buf][hd,hp,U,V]
  __shared__ __align__(16) unsigned exch2[4096];   // 16 KB exchange

  const int tid  = threadIdx.x;
  const int lane = tid & 63;
  const int wid  = tid >> 6;
  const int role = wid >> 2;              // 0 = u (hd*U), 1 = v (hp*V)
  const int w4   = wid & 3;
  const int wm   = w4 >> 1;               // 0..1
  const int wn   = w4 & 1;                // 0..1

  const int bx = blockIdx.x;              // 0..31 (XCD = bx%8)
  const int jt = blockIdx.y;              // 0..7

  const u16* hdp = hdf + (size_t)bx * 16 * 8192;     // [kt][1024 chunks][8]
  const u16* hpp = hpf + (size_t)bx * 16 * 8192;
  const u16* Ub  = Uf + (size_t)jt * 16 * 8192;      // + r*rstride + kt*8192
  const u16* Vb  = Vf + (size_t)jt * 16 * 8192;
  const size_t rstride = (size_t)8 * 16 * 8192;

  const int c0 = tid;                     // staging chunks per tensor
  const int c1 = tid + 512;

  f32x16 acc[2][2], aw[2][2];
  #pragma unroll
  for (int mf = 0; mf < 2; ++mf)
    #pragma unroll
    for (int nf = 0; nf < 2; ++nf) {
      #pragma unroll
      for (int i = 0; i < 16; ++i) { acc[mf][nf][i] = 0.f; aw[mf][nf][i] = 0.f; }
    }

  // prologue: stage step 0 into buf 0.
  STAGE_A(0, 0);
  STAGE_B(0, 0);
  __syncthreads();

  #pragma unroll 1
  for (int it = 0; it < 128; ++it) {
    const int s0 = it * 2;
    const int s1 = s0 + 1;

    // even step: stage s1 into buf 1 (issued before compute), compute buf 0
    STAGE_A(1, s1);
    STAGE_B(1, s1);
    COMPUTE(0);
    __syncthreads();

    // odd step: stage s1+1 into buf 0 (uniform, incl. boundaries), compute buf 1
    if (s1 < 255) {
      STAGE_A(0, s1 + 1);
      STAGE_B(0, s1 + 1);
    }
    COMPUTE(1);
    const bool bound = ((s1 & 15) == 15);
    if (bound) {
      // 2-round exchange through dedicated exch2 (r12-proven structure)
      #pragma unroll
      for (int g = 0; g < 2; ++g) {
        if (role) {                       // v-waves publish aw[g][*] as bf16
          #pragma unroll
          for (int nf = 0; nf < 2; ++nf)
            #pragma unroll
            for (int rp = 0; rp < 8; ++rp) {
              const unsigned lo = f2b(aw[g][nf][2 * rp]);
              const unsigned hi = f2b(aw[g][nf][2 * rp + 1]);
              exch2[((w4 * 2 + nf) * 8 + rp) * 64 + lane] = lo | (hi << 16);
            }
          asm volatile("s_waitcnt lgkmcnt(0)" ::: "memory");
        }
        BAR();
        if (!role) {                      // u-waves: acc += au * av
          #pragma unroll
          for (int nf = 0; nf < 2; ++nf)
            #pragma unroll
            for (int rp = 0; rp < 8; ++rp) {
              const unsigned w = exch2[((w4 * 2 + nf) * 8 + rp) * 64 + lane];
              acc[g][nf][2 * rp]     += aw[g][nf][2 * rp]     * b2f((u16)(w & 0xFFFFu));
              acc[g][nf][2 * rp + 1] += aw[g][nf][2 * rp + 1] * b2f((u16)(w >> 16));
            }
          asm volatile("s_waitcnt lgkmcnt(0)" ::: "memory");
        }
        if (g == 0) BAR();                // round-0 consumed before re-publish
      }
      // reset rank accumulators
      #pragma unroll
      for (int mf = 0; mf < 2; ++mf)
        #pragma unroll
        for (int nf = 0; nf < 2; ++nf)
          #pragma unroll
          for (int i = 0; i < 16; ++i) aw[mf][nf][i] = 0.f;
    }
    __syncthreads();                      // drains stage; buf 0 ready
  }

  // epilogue: u-waves store RAW rank-sum (ReLU in LN).
  // D-layout 32x32: col = lane&31, row = (reg&3) + 8*(reg>>2) + 4*(lane>>5).
  if (!role) {
    const int brow = bx * 128 + wm * 64;
    const int jcol = jt * 128 + wn * 64;
    #pragma unroll
    for (int mf = 0; mf < 2; ++mf)
      #pragma unroll
      for (int nf = 0; nf < 2; ++nf) {
        #pragma unroll
        for (int i = 0; i < 16; ++i) {
          const int row = brow + mf * 32 + (i & 3) + 8 * (i >> 2) + 4 * (lane >> 5);
          const int col = jcol + nf * 32 + (lane & 31);
          out[(size_t)row * Zq + col] = acc[mf][nf][i];
        }
      }
  }
}

// ---- LayerNorm: z = relu(p); LN(z) -> out, in place. jnp.var ddof=0. ----
__global__ __launch_bounds__(256) void ln_rows(float* __restrict__ out,
    const float* __restrict__ gamma, const float* __restrict__ beta)
{
  const int row = blockIdx.x;
  const int t = threadIdx.x;
  float* o = out + (size_t)row * Zq;
  float4 v = ((const float4*)o)[t];
  v.x = fmaxf(v.x, 0.f); v.y = fmaxf(v.y, 0.f);
  v.z = fmaxf(v.z, 0.f); v.w = fmaxf(v.w, 0.f);
  float s = v.x + v.y + v.z + v.w;
  float q = v.x * v.x + v.y * v.y + v.z * v.z + v.w * v.w;
  #pragma unroll
  for (int off = 32; off > 0; off >>= 1) {
    s += __shfl_xor(s, off);
    q += __shfl_xor(q, off);
  }
  __shared__ float ss[4], sq[4];
  if ((t & 63) == 0) { ss[t >> 6] = s; sq[t >> 6] = q; }
  __syncthreads();
  s = ss[0] + ss[1] + ss[2] + ss[3];
  q = sq[0] + sq[1] + sq[2] + sq[3];
  const float mean = s * (1.f / Zq);
  float var = q * (1.f / Zq) - mean * mean;
  var = fmaxf(var, 0.f);
  const float rstd = rsqrtf(var + 1e-5f);
  const float4 g  = ((const float4*)gamma)[t];
  const float4 bb = ((const float4*)beta)[t];
  v.x = (v.x - mean) * rstd * g.x + bb.x;
  v.y = (v.y - mean) * rstd * g.y + bb.y;
  v.z = (v.z - mean) * rstd * g.z + bb.z;
  v.w = (v.w - mean) * rstd * g.w + bb.w;
  ((float4*)o)[t] = v;
}

// ---- fallback (tiny ws): plain f32, correct but slow ----
__global__ __launch_bounds__(256) void fallback_bilinear(
    const float* __restrict__ hd, const float* __restrict__ hp,
    const float* __restrict__ U, const float* __restrict__ V,
    float* __restrict__ out)
{
  const int j  = blockIdx.x * 256 + threadIdx.x;
  const int b0 = blockIdx.y * 8;
  float acc[8] = {0.f, 0.f, 0.f, 0.f, 0.f, 0.f, 0.f, 0.f};
  for (int r = 0; r < Rk; ++r) {
    float u[8] = {0.f}, v[8] = {0.f};
    const float* Up = U + (size_t)r * (D * Zq) + j;
    const float* Vp = V + (size_t)r * (D * Zq) + j;
    for (int k = 0; k < D; ++k) {
      const float uu = Up[(size_t)k * Zq];
      const float vv = Vp[(size_t)k * Zq];
      #pragma unroll
      for (int bi = 0; bi < 8; ++bi) {
        u[bi] = fmaf(hd[(size_t)(b0 + bi) * D + k], uu, u[bi]);
        v[bi] = fmaf(hp[(size_t)(b0 + bi) * D + k], vv, v[bi]);
      }
    }
    #pragma unroll
    for (int bi = 0; bi < 8; ++bi) acc[bi] += u[bi] * v[bi];
  }
  #pragma unroll
  for (int bi = 0; bi < 8; ++bi)
    out[(size_t)(b0 + bi) * Zq + j] = acc[bi];   // raw; ReLU in LN
}

extern "C" void kernel_launch(void* const* d_in, const int* in_sizes, int n_in,
                              void* d_out, int out_size, void* d_ws, size_t ws_size,
                              hipStream_t stream) {
  const float* hd    = (const float*)d_in[0];   // [4096][1024]
  const float* hp    = (const float*)d_in[1];   // [4096][1024]
  const float* U     = (const float*)d_in[2];   // [16][1024][1024]
  const float* V     = (const float*)d_in[3];   // [16][1024][1024]
  const float* gamma = (const float*)d_in[4];   // [1024]
  const float* beta  = (const float*)d_in[5];   // [1024]
  float* out = (float*)d_out;                   // [4096][1024] f32

  const size_t need = 80ull << 20;  // hd,hp fm (16MB) + U,V fm (64MB)
  if (ws_size >= need) {
    u16* hdf = (u16*)d_ws;                   // 4M elems
    u16* hpf = hdf + (size_t)Bq * D;
    u16* Ufm = hpf + (size_t)Bq * D;         // 16M elems each
    u16* Vfm = Ufm + (size_t)Rk * D * Zq;

    fm_pack_A2<<<dim3(2048, 2), 256, 0, stream>>>(hd, hp, hdf, hpf);
    fm_pack_B2<<<dim3(8192, 2), 256, 0, stream>>>(U, V, Ufm, Vfm);
    fused_bilinear<<<dim3(32, 8), 512, 0, stream>>>(hdf, hpf, Ufm, Vfm, out);
  } else {
    fallback_bilinear<<<dim3(Zq / 256, Bq / 8), 256, 0, stream>>>(hd, hp, U, V, out);
  }
  ln_rows<<<Bq, 256, 0, stream>>>(out, gamma, beta);
}

// Round 14
// 342.246 us; speedup vs baseline: 1.0982x; 1.0501x over previous
//
#include <hip/hip_runtime.h>

// MUTAN fused bilinear (low-rank Tucker) + ReLU + LayerNorm, MI355X gfx950.
// Round 14: exact revert to the round-11 winner (fused 308us, MfmaUtil 41%):
// role-split u/v waves, 32x32x16 MFMA, all tensors via global_load_lds,
// single __syncthreads per K-step, rank-boundary Hadamard exchange through
// the idle buffer's B-slots. Only delta vs r11: merged prep launches.
// r12 (counted-vmcnt retrofit) and r13 (dedicated exch buffer) both
// regressed: added barriers/serialization at 2-waves/SIMD occupancy.

typedef unsigned short u16;
typedef __attribute__((ext_vector_type(8)))  short bf16x8;   // 8 bf16
typedef __attribute__((ext_vector_type(16))) float f32x16;   // 32x32 MFMA C/D

constexpr int Bq = 4096;   // batch
constexpr int D  = 1024;   // contraction dim
constexpr int Zq = 1024;   // output dim
constexpr int Rk = 16;     // rank
// A pack: [bx(32)][kt(16)][chunk(1024)][8]; chunk = (mfb*4+ks)*64 + lane
//   row = bx*128 + mfb*32 + (l&31), k = kt*64 + ks*16 + 8*(l>>5) + e
// B pack: [r(16)][jt(8)][kt(16)][chunk(1024)][8]; chunk = (nfb*4+ks)*64 + lane
// 32x32x16 frags: A[l&31][8*(l>>5)+e]; B[8*(l>>5)+e][l&31];
// C/D (verified m74/m101): col = lane&31, row = (reg&3)+8*(reg>>2)+4*(lane>>5).

typedef const __attribute__((address_space(1))) void* gas_t;
typedef __attribute__((address_space(3))) void* las_t;

__device__ __forceinline__ u16 f2b(float f) {
  union { float f; unsigned u; } c; c.f = f;
  unsigned r = (c.u + 0x7FFFu + ((c.u >> 16) & 1u)) >> 16;  // RNE
  return (u16)r;
}
__device__ __forceinline__ float b2f(u16 h) {
  union { unsigned u; float f; } c; c.u = ((unsigned)h) << 16; return c.f;
}

// ---- prep: hd & hp [4096][1024] f32 -> fragment-major bf16 (merged) ----
__global__ __launch_bounds__(256) void fm_pack_A2(const float* __restrict__ sA,
                                                  const float* __restrict__ sB,
                                                  u16* __restrict__ dA,
                                                  u16* __restrict__ dB) {
  const float* src = blockIdx.y ? sB : sA;
  u16* dst = blockIdx.y ? dB : dA;
  const int g  = blockIdx.x * 256 + threadIdx.x;      // chunk id (524288)
  const int c  = g & 1023;
  const int kt = (g >> 10) & 15;
  const int bx = g >> 14;
  const int l   = c & 63;
  const int ks  = (c >> 6) & 3;
  const int mfb = c >> 8;                              // 0..3
  const int row = bx * 128 + mfb * 32 + (l & 31);
  const int kb  = kt * 64 + ks * 16 + ((l >> 5) << 3);
  const float* s = src + (size_t)row * D + kb;
  const float4 f0 = *(const float4*)s;
  const float4 f1 = *(const float4*)(s + 4);
  union { u16 h[8]; uint4 u; } o;
  o.h[0] = f2b(f0.x); o.h[1] = f2b(f0.y); o.h[2] = f2b(f0.z); o.h[3] = f2b(f0.w);
  o.h[4] = f2b(f1.x); o.h[5] = f2b(f1.y); o.h[6] = f2b(f1.z); o.h[7] = f2b(f1.w);
  *(uint4*)(dst + (size_t)g * 8) = o.u;
}

// ---- prep: U & V [r][k][z] f32 -> fragment-major bf16 (merged) ----
__global__ __launch_bounds__(256) void fm_pack_B2(const float* __restrict__ sU,
                                                  const float* __restrict__ sV,
                                                  u16* __restrict__ dU,
                                                  u16* __restrict__ dV) {
  const float* src = blockIdx.y ? sV : sU;
  u16* dst = blockIdx.y ? dV : dU;
  const int g  = blockIdx.x * 256 + threadIdx.x;      // chunk id (2097152)
  const int c  = g & 1023;
  const int kt = (g >> 10) & 15;
  const int jt = (g >> 14) & 7;
  const int r  = g >> 17;
  const int l   = c & 63;
  const int ks  = (c >> 6) & 3;
  const int nfb = c >> 8;                              // 0..3
  const int col = jt * 128 + nfb * 32 + (l & 31);
  const int kg  = kt * 64 + ks * 16 + ((l >> 5) << 3);
  const float* s = src + (size_t)r * (D * Zq) + (size_t)kg * Zq + col;
  union { u16 h[8]; uint4 u; } o;
  #pragma unroll
  for (int e = 0; e < 8; ++e) o.h[e] = f2b(s[(size_t)e * Zq]);
  *(uint4*)(dst + (size_t)g * 8) = o.u;
}

#define GLDS(src, dst) __builtin_amdgcn_global_load_lds((gas_t)(src), (las_t)(dst), 16, 0, 0)
#define MFMA32(a, b, c) __builtin_amdgcn_mfma_f32_32x32x16_bf16(a, b, c, 0, 0, 0)

#define STAGE_A(buf, st) do {                                                    \
    const int _kt = (st) & 15;                                                   \
    GLDS(hdp + _kt * 8192 + c0 * 8, &sT[buf][0][c0 * 8]);                        \
    GLDS(hdp + _kt * 8192 + c1 * 8, &sT[buf][0][c1 * 8]);                        \
    GLDS(hpp + _kt * 8192 + c0 * 8, &sT[buf][1][c0 * 8]);                        \
    GLDS(hpp + _kt * 8192 + c1 * 8, &sT[buf][1][c1 * 8]);                        \
  } while (0)

#define STAGE_B(buf, st) do {                                                    \
    const int _kt = (st) & 15;                                                   \
    const u16* _u = Ub + (size_t)((st) >> 4) * rstride + _kt * 8192;             \
    const u16* _v = Vb + (size_t)((st) >> 4) * rstride + _kt * 8192;             \
    GLDS(_u + c0 * 8, &sT[buf][2][c0 * 8]);                                      \
    GLDS(_u + c1 * 8, &sT[buf][2][c1 * 8]);                                      \
    GLDS(_v + c0 * 8, &sT[buf][3][c0 * 8]);                                      \
    GLDS(_v + c1 * 8, &sT[buf][3][c1 * 8]);                                      \
  } while (0)

// role-split compute: each wave reads ONE A tensor + ONE B tensor, 16 MFMA.
#define COMPUTE(buf) do {                                                        \
    const u16* tA = sT[buf][role];                                               \
    const u16* tB = sT[buf][2 + role];                                           \
    _Pragma("unroll")                                                            \
    for (int ks = 0; ks < 4; ++ks) {                                             \
      bf16x8 a0 = *(const bf16x8*)(tA + (((wm * 2 + 0) * 4 + ks) * 64 + lane) * 8); \
      bf16x8 a1 = *(const bf16x8*)(tA + (((wm * 2 + 1) * 4 + ks) * 64 + lane) * 8); \
      bf16x8 b0 = *(const bf16x8*)(tB + (((wn * 2 + 0) * 4 + ks) * 64 + lane) * 8); \
      bf16x8 b1 = *(const bf16x8*)(tB + (((wn * 2 + 1) * 4 + ks) * 64 + lane) * 8); \
      __builtin_amdgcn_s_setprio(1);                                             \
      aw[0][0] = MFMA32(a0, b0, aw[0][0]);                                       \
      aw[0][1] = MFMA32(a0, b1, aw[0][1]);                                       \
      aw[1][0] = MFMA32(a1, b0, aw[1][0]);                                       \
      aw[1][1] = MFMA32(a1, b1, aw[1][1]);                                       \
      __builtin_amdgcn_s_setprio(0);                                             \
    }                                                                            \
  } while (0)

// ---- main: fused bilinear, role-split 32x32x16 MFMA (round-11 exact) ----
// grid (32 bx, 8 jt) = 256 blocks = 1/CU. 512 thr = 8 waves: 0-3 u-GEMM
// (hd*U), 4-7 v-GEMM (hp*V); wave tile 64x64 (2x2 frags of 32x32).
// Rank-boundary: v-waves publish av (bf16) via idle buf-0 B-slots,
// u-waves acc += au*av.
__global__ __launch_bounds__(512, 2) void fused_bilinear(
    const u16* __restrict__ hdf, const u16* __restrict__ hpf,
    const u16* __restrict__ Uf, const u16* __restrict__ Vf,
    float* __restrict__ out)
{
  __shared__ __align__(16) u16 sT[2][4][8192];   // 128 KB: [buf][hd,hp,U,V]

  const int tid  = threadIdx.x;
  const int lane = tid & 63;
  const int wid  = tid >> 6;
  const int role = wid >> 2;              // 0 = u (hd*U), 1 = v (hp*V)
  const int w4   = wid & 3;
  const int wm   = w4 >> 1;               // 0..1
  const int wn   = w4 & 1;                // 0..1

  const int bx = blockIdx.x;              // 0..31 (XCD = bx%8)
  const int jt = blockIdx.y;              // 0..7

  const u16* hdp = hdf + (size_t)bx * 16 * 8192;     // [kt][1024 chunks][8]
  const u16* hpp = hpf + (size_t)bx * 16 * 8192;
  const u16* Ub  = Uf + (size_t)jt * 16 * 8192;      // + r*rstride + kt*8192
  const u16* Vb  = Vf + (size_t)jt * 16 * 8192;
  const size_t rstride = (size_t)8 * 16 * 8192;

  const int c0 = tid;                     // staging chunks per tensor
  const int c1 = tid + 512;

  f32x16 acc[2][2], aw[2][2];
  #pragma unroll
  for (int mf = 0; mf < 2; ++mf)
    #pragma unroll
    for (int nf = 0; nf < 2; ++nf) {
      #pragma unroll
      for (int i = 0; i < 16; ++i) { acc[mf][nf][i] = 0.f; aw[mf][nf][i] = 0.f; }
    }

  // exchange buffer: B-slots of buf 0 (boundary steps are odd -> buf 1 active)
  unsigned* exch = (unsigned*)&sT[0][2][0];          // 8192 u32 = 32 KB

  // prologue: stage step 0 into buf 0.
  STAGE_A(0, 0);
  STAGE_B(0, 0);
  __syncthreads();

  #pragma unroll 1
  for (int it = 0; it < 128; ++it) {
    const int s0 = it * 2;
    const int s1 = s0 + 1;

    // even step: compute buf 0, stage s1 into buf 1
    STAGE_A(1, s1);
    STAGE_B(1, s1);
    COMPUTE(0);
    __syncthreads();

    // odd step: compute buf 1, stage s1+1 into buf 0
    const bool bound = ((s1 & 15) == 15);
    if (s1 < 255) {
      STAGE_A(0, s1 + 1);
      if (!bound) STAGE_B(0, s1 + 1);
    }
    COMPUTE(1);
    if (bound) {
      __syncthreads();                 // buf-0 reads (prev even step) long done;
                                       // buf-1 reads done; exch region idle
      if (role) {                      // v-waves: publish av as bf16
        #pragma unroll
        for (int mf = 0; mf < 2; ++mf)
          #pragma unroll
          for (int nf = 0; nf < 2; ++nf) {
            const int f = mf * 2 + nf;
            #pragma unroll
            for (int rp = 0; rp < 8; ++rp) {
              const unsigned lo = f2b(aw[mf][nf][2 * rp]);
              const unsigned hi = f2b(aw[mf][nf][2 * rp + 1]);
              exch[((w4 * 4 + f) * 8 + rp) * 64 + lane] = lo | (hi << 16);
            }
          }
      }
      __syncthreads();
      if (!role) {                     // u-waves: acc += au * av
        #pragma unroll
        for (int mf = 0; mf < 2; ++mf)
          #pragma unroll
          for (int nf = 0; nf < 2; ++nf) {
            const int f = mf * 2 + nf;
            #pragma unroll
            for (int rp = 0; rp < 8; ++rp) {
              const unsigned w = exch[((w4 * 4 + f) * 8 + rp) * 64 + lane];
              acc[mf][nf][2 * rp]     += aw[mf][nf][2 * rp]     * b2f((u16)(w & 0xFFFFu));
              acc[mf][nf][2 * rp + 1] += aw[mf][nf][2 * rp + 1] * b2f((u16)(w >> 16));
            }
          }
      }
      #pragma unroll
      for (int mf = 0; mf < 2; ++mf)
        #pragma unroll
        for (int nf = 0; nf < 2; ++nf)
          #pragma unroll
          for (int i = 0; i < 16; ++i) aw[mf][nf][i] = 0.f;
      __syncthreads();                 // exchange consumed; exch region free
      if (s1 < 255) STAGE_B(0, s1 + 1);
      __syncthreads();                 // drain late B stage (+ pending A stage)
    } else {
      __syncthreads();
    }
  }

  // epilogue: u-waves store RAW rank-sum (ReLU in LN).
  // D-layout 32x32: col = lane&31, row = (reg&3) + 8*(reg>>2) + 4*(lane>>5).
  if (!role) {
    const int brow = bx * 128 + wm * 64;
    const int jcol = jt * 128 + wn * 64;
    #pragma unroll
    for (int mf = 0; mf < 2; ++mf)
      #pragma unroll
      for (int nf = 0; nf < 2; ++nf) {
        #pragma unroll
        for (int i = 0; i < 16; ++i) {
          const int row = brow + mf * 32 + (i & 3) + 8 * (i >> 2) + 4 * (lane >> 5);
          const int col = jcol + nf * 32 + (lane & 31);
          out[(size_t)row * Zq + col] = acc[mf][nf][i];
        }
      }
  }
}

// ---- LayerNorm: z = relu(p); LN(z) -> out, in place. jnp.var ddof=0. ----
__global__ __launch_bounds__(256) void ln_rows(float* __restrict__ out,
    const float* __restrict__ gamma, const float* __restrict__ beta)
{
  const int row = blockIdx.x;
  const int t = threadIdx.x;
  float* o = out + (size_t)row * Zq;
  float4 v = ((const float4*)o)[t];
  v.x = fmaxf(v.x, 0.f); v.y = fmaxf(v.y, 0.f);
  v.z = fmaxf(v.z, 0.f); v.w = fmaxf(v.w, 0.f);
  float s = v.x + v.y + v.z + v.w;
  float q = v.x * v.x + v.y * v.y + v.z * v.z + v.w * v.w;
  #pragma unroll
  for (int off = 32; off > 0; off >>= 1) {
    s += __shfl_xor(s, off);
    q += __shfl_xor(q, off);
  }
  __shared__ float ss[4], sq[4];
  if ((t & 63) == 0) { ss[t >> 6] = s; sq[t >> 6] = q; }
  __syncthreads();
  s = ss[0] + ss[1] + ss[2] + ss[3];
  q = sq[0] + sq[1] + sq[2] + sq[3];
  const float mean = s * (1.f / Zq);
  float var = q * (1.f / Zq) - mean * mean;
  var = fmaxf(var, 0.f);
  const float rstd = rsqrtf(var + 1e-5f);
  const float4 g  = ((const float4*)gamma)[t];
  const float4 bb = ((const float4*)beta)[t];
  v.x = (v.x - mean) * rstd * g.x + bb.x;
  v.y = (v.y - mean) * rstd * g.y + bb.y;
  v.z = (v.z - mean) * rstd * g.z + bb.z;
  v.w = (v.w - mean) * rstd * g.w + bb.w;
  ((float4*)o)[t] = v;
}

// ---- fallback (tiny ws): plain f32, correct but slow ----
__global__ __launch_bounds__(256) void fallback_bilinear(
    const float* __restrict__ hd, const float* __restrict__ hp,
    const float* __restrict__ U, const float* __restrict__ V,
    float* __restrict__ out)
{
  const int j  = blockIdx.x * 256 + threadIdx.x;
  const int b0 = blockIdx.y * 8;
  float acc[8] = {0.f, 0.f, 0.f, 0.f, 0.f, 0.f, 0.f, 0.f};
  for (int r = 0; r < Rk; ++r) {
    float u[8] = {0.f}, v[8] = {0.f};
    const float* Up = U + (size_t)r * (D * Zq) + j;
    const float* Vp = V + (size_t)r * (D * Zq) + j;
    for (int k = 0; k < D; ++k) {
      const float uu = Up[(size_t)k * Zq];
      const float vv = Vp[(size_t)k * Zq];
      #pragma unroll
      for (int bi = 0; bi < 8; ++bi) {
        u[bi] = fmaf(hd[(size_t)(b0 + bi) * D + k], uu, u[bi]);
        v[bi] = fmaf(hp[(size_t)(b0 + bi) * D + k], vv, v[bi]);
      }
    }
    #pragma unroll
    for (int bi = 0; bi < 8; ++bi) acc[bi] += u[bi] * v[bi];
  }
  #pragma unroll
  for (int bi = 0; bi < 8; ++bi)
    out[(size_t)(b0 + bi) * Zq + j] = acc[bi];   // raw; ReLU in LN
}

extern "C" void kernel_launch(void* const* d_in, const int* in_sizes, int n_in,
                              void* d_out, int out_size, void* d_ws, size_t ws_size,
                              hipStream_t stream) {
  const float* hd    = (const float*)d_in[0];   // [4096][1024]
  const float* hp    = (const float*)d_in[1];   // [4096][1024]
  const float* U     = (const float*)d_in[2];   // [16][1024][1024]
  const float* V     = (const float*)d_in[3];   // [16][1024][1024]
  const float* gamma = (const float*)d_in[4];   // [1024]
  const float* beta  = (const float*)d_in[5];   // [1024]
  float* out = (float*)d_out;                   // [4096][1024] f32

  const size_t need = 80ull << 20;  // hd,hp fm (16MB) + U,V fm (64MB)
  if (ws_size >= need) {
    u16* hdf = (u16*)d_ws;                   // 4M elems
    u16* hpf = hdf + (size_t)Bq * D;
    u16* Ufm = hpf + (size_t)Bq * D;         // 16M elems each
    u16* Vfm = Ufm + (size_t)Rk * D * Zq;

    fm_pack_A2<<<dim3(2048, 2), 256, 0, stream>>>(hd, hp, hdf, hpf);
    fm_pack_B2<<<dim3(8192, 2), 256, 0, stream>>>(U, V, Ufm, Vfm);
    fused_bilinear<<<dim3(32, 8), 512, 0, stream>>>(hdf, hpf, Ufm, Vfm, out);
  } else {
    fallback_bilinear<<<dim3(Zq / 256, Bq / 8), 256, 0, stream>>>(hd, hp, U, V, out);
  }
  ln_rows<<<Bq, 256, 0, stream>>>(out, gamma, beta);
}